// Round 11
// baseline (542.637 us; speedup 1.0000x reference)
//
#include <hip/hip_runtime.h>
#include <hip/hip_fp16.h>

// RecLGN: 3-layer weighted LightGCN on bipartite user-recipe graph.
// v11: scalar-path pair loads (uniform addr -> s_load_dwordx4, frees VMEM
// pipe for row gathers), simplified 16/4 gather loop. Otherwise v10:
// pad-to-4 rows, NT streaming epilogues, atomic-free bucket-sort CSR build.

typedef unsigned long long ull;
typedef float float2v __attribute__((ext_vector_type(2)));

constexpr int NU   = 100000;
constexpr int NR   = 200000;
constexpr int EMB  = 32;
constexpr int RDIM = 96;
constexpr int D    = 128;
constexpr int NE   = 1500000;
constexpr float ALPHA = 0.25f;  // 1/(NUM_LAYERS+1)

constexpr ull DEG_MASK = (1ULL << 44) - 1;
constexpr float DEG_SCALE = 1048576.0f;   // 2^20
constexpr float DEG_INV   = 1.0f / 1048576.0f;

// bucket decomposition
constexpr int NBK    = 391;
constexpr int SPAN_R = 512;   // r >> 9
constexpr int SPAN_U = 256;   // u >> 8
constexpr int EPB    = 4096;
constexpr int B1     = (NE + EPB - 1) / EPB;
constexpr int CB     = (NU * D / 16 + 255) / 256;

// ---- bf16 helpers --------------------------------------------------------

__device__ __forceinline__ unsigned pack_bf16x2(float x, float y) {
    unsigned ux = __float_as_uint(x);
    unsigned uy = __float_as_uint(y);
    ux += 0x7fffu + ((ux >> 16) & 1u);
    uy += 0x7fffu + ((uy >> 16) & 1u);
    return (ux >> 16) | (uy & 0xffff0000u);
}

__device__ __forceinline__ float blo(unsigned u) { return __uint_as_float(u << 16); }
__device__ __forceinline__ float bhi(unsigned u) { return __uint_as_float(u & 0xffff0000u); }

// ---- K1: per-block LDS histograms (+ usr_emb bf16 convert) ---------------

__global__ void hist_kernel(const int* __restrict__ ui,
                            const int* __restrict__ ri,
                            unsigned* __restrict__ hist_u,
                            unsigned* __restrict__ hist_r,
                            const float4* __restrict__ usr_emb4,
                            uint4* __restrict__ emb_h4) {
    if ((int)blockIdx.x >= B1) {
        int t = ((int)blockIdx.x - B1) * 256 + threadIdx.x;
        if (t < NU * D / 16) {
            int base = t * 4;
            float4 a = usr_emb4[base], b = usr_emb4[base + 1];
            float4 c = usr_emb4[base + 2], d = usr_emb4[base + 3];
            uint4 o0 = {pack_bf16x2(a.x, a.y), pack_bf16x2(a.z, a.w),
                        pack_bf16x2(b.x, b.y), pack_bf16x2(b.z, b.w)};
            uint4 o1 = {pack_bf16x2(c.x, c.y), pack_bf16x2(c.z, c.w),
                        pack_bf16x2(d.x, d.y), pack_bf16x2(d.z, d.w)};
            emb_h4[t * 2]     = o0;
            emb_h4[t * 2 + 1] = o1;
        }
        return;
    }
    __shared__ unsigned hu[NBK], hr[NBK];
    for (int j = threadIdx.x; j < NBK; j += 256) { hu[j] = 0; hr[j] = 0; }
    __syncthreads();
    int base = blockIdx.x * EPB;
    for (int k = 0; k < 16; ++k) {
        int i = base + k * 256 + threadIdx.x;
        if (i < NE) {
            atomicAdd(&hu[ui[i] >> 8], 1u);
            atomicAdd(&hr[ri[i] >> 9], 1u);
        }
    }
    __syncthreads();
    for (int j = threadIdx.x; j < NBK; j += 256) {
        hist_u[j * B1 + blockIdx.x] = hu[j];
        hist_r[j * B1 + blockIdx.x] = hr[j];
    }
}

// ---- K2a/K2b: bucket scans ------------------------------------------------

__global__ void scan_hist(unsigned* __restrict__ hist_r,
                          unsigned* __restrict__ hist_u,
                          unsigned* __restrict__ btot) {
    __shared__ unsigned tmp[512];
    bool isR = (int)blockIdx.x < NBK;
    int j = isR ? (int)blockIdx.x : (int)blockIdx.x - NBK;
    unsigned* h = (isR ? hist_r : hist_u) + (size_t)j * B1;
    int i = threadIdx.x;
    unsigned v = (i < B1) ? h[i] : 0;
    tmp[i] = v;
    __syncthreads();
    for (int o = 1; o < 512; o <<= 1) {
        unsigned t = (i >= o) ? tmp[i - o] : 0;
        __syncthreads();
        tmp[i] += t;
        __syncthreads();
    }
    if (i < B1) h[i] = tmp[i] - v;
    if (i == 511) btot[blockIdx.x] = tmp[511];
}

__global__ void scan_btot(const unsigned* __restrict__ btot,
                          unsigned* __restrict__ boff_r,
                          unsigned* __restrict__ boff_u) {
    __shared__ unsigned tmp[512];
    bool isR = (blockIdx.x == 0);
    unsigned* boff = isR ? boff_r : boff_u;
    int i = threadIdx.x;
    unsigned v = (i < NBK) ? btot[(isR ? 0 : NBK) + i] : 0;
    tmp[i] = v;
    __syncthreads();
    for (int o = 1; o < 512; o <<= 1) {
        unsigned t = (i >= o) ? tmp[i - o] : 0;
        __syncthreads();
        tmp[i] += t;
        __syncthreads();
    }
    if (i < NBK) boff[i] = tmp[i] - v;
    if (i == 0) boff[NBK] = tmp[511];
}

// ---- K3: scatter into bucket regions (LDS cursors) -----------------------

__global__ void scatter_kernel(const int* __restrict__ ui,
                               const int* __restrict__ ri,
                               const float* __restrict__ w,
                               const unsigned* __restrict__ hist_u,
                               const unsigned* __restrict__ hist_r,
                               const unsigned* __restrict__ boff_u,
                               const unsigned* __restrict__ boff_r,
                               ull* __restrict__ buf_u,
                               ull* __restrict__ buf_r) {
    __shared__ unsigned cu[NBK], cr[NBK];
    for (int j = threadIdx.x; j < NBK; j += 256) {
        cu[j] = boff_u[j] + hist_u[j * B1 + blockIdx.x];
        cr[j] = boff_r[j] + hist_r[j * B1 + blockIdx.x];
    }
    __syncthreads();
    int base = blockIdx.x * EPB;
    for (int k = 0; k < 16; ++k) {
        int i = base + k * 256 + threadIdx.x;
        if (i < NE) {
            int u = ui[i], r = ri[i];
            ull wh = (ull)__half_as_ushort(__float2half(w[i]));
            ull rec_r = (ull)(unsigned)u | ((ull)(r & 511) << 18) | (wh << 32);
            ull rec_u = (ull)(unsigned)r | ((ull)(u & 255) << 18) | (wh << 32);
            unsigned sr = atomicAdd(&cr[r >> 9], 1u);
            unsigned su = atomicAdd(&cu[u >> 8], 1u);
            buf_r[sr] = rec_r;
            buf_u[su] = rec_u;
        }
    }
}

// ---- K4a: per-bucket count + weighted degree -> pk -----------------------

__global__ void count_kernel(const ull* __restrict__ buf_r,
                             const ull* __restrict__ buf_u,
                             const unsigned* __restrict__ boff_r,
                             const unsigned* __restrict__ boff_u,
                             ull* __restrict__ pk_r,
                             ull* __restrict__ pk_u) {
    bool isR = (int)blockIdx.x < NBK;
    int j = isR ? (int)blockIdx.x : (int)blockIdx.x - NBK;
    const ull* buf = isR ? buf_r : buf_u;
    const unsigned* boff = isR ? boff_r : boff_u;
    ull* pk = isR ? pk_r : pk_u;
    int span = isR ? SPAN_R : SPAN_U;
    int nnode = isR ? NR : NU;
    __shared__ unsigned cnt[512], wfx[512];
    for (int i = threadIdx.x; i < span; i += 256) { cnt[i] = 0; wfx[i] = 0; }
    __syncthreads();
    unsigned beg = boff[j], end = boff[j + 1];
    for (unsigned e = beg + threadIdx.x; e < end; e += 256) {
        ull rec = buf[e];
        int dlow = (int)((rec >> 18) & 511);
        float wv = __half2float(__ushort_as_half((unsigned short)(rec >> 32)));
        atomicAdd(&cnt[dlow], 1u);
        atomicAdd(&wfx[dlow], (unsigned)(wv * DEG_SCALE + 0.5f));
    }
    __syncthreads();
    int nb = j * span;
    for (int i = threadIdx.x; i < span; i += 256) {
        int node = nb + i;
        if (node < nnode) pk[node] = ((ull)cnt[i] << 44) | (ull)wfx[i];
    }
}

// ---- CSR scans (pad rows to multiple of 4) -------------------------------

__global__ void scan_block_both(const ull* __restrict__ pk_r,
                                const ull* __restrict__ pk_u,
                                int* __restrict__ rp_r,
                                int* __restrict__ rp_u,
                                int* __restrict__ bsum, int nbR) {
    __shared__ int tmp[256];
    bool isR = (int)blockIdx.x < nbR;
    const ull* pk = isR ? pk_r : pk_u;
    int* excl = isR ? rp_r : rp_u;
    int ncnt  = isR ? NR : NU;
    int b     = isR ? (int)blockIdx.x : (int)blockIdx.x - nbR;
    int nscan = ncnt + 1;
    int i = b * 256 + threadIdx.x;
    int v = 0;
    if (i < ncnt) v = ((int)(pk[i] >> 44) + 3) & ~3;
    tmp[threadIdx.x] = v;
    __syncthreads();
    for (int off = 1; off < 256; off <<= 1) {
        int t = (threadIdx.x >= off) ? tmp[threadIdx.x - off] : 0;
        __syncthreads();
        tmp[threadIdx.x] += t;
        __syncthreads();
    }
    if (i < nscan) excl[i] = tmp[threadIdx.x] - v;
    if (threadIdx.x == 255) bsum[blockIdx.x] = tmp[255];
}

__global__ void scan_bsum2(int* __restrict__ bsum, int nbR, int nbU) {
    __shared__ int tmp[1024];
    int off = (blockIdx.x == 0) ? 0 : nbR;
    int nb  = (blockIdx.x == 0) ? nbR : nbU;
    int i = threadIdx.x;
    int v = (i < nb) ? bsum[off + i] : 0;
    tmp[i] = v;
    __syncthreads();
    for (int o = 1; o < 1024; o <<= 1) {
        int t = (i >= o) ? tmp[i - o] : 0;
        __syncthreads();
        tmp[i] += t;
        __syncthreads();
    }
    if (i < nb) bsum[off + i] = tmp[i] - v;
}

__global__ void finalize_both(const int* __restrict__ rp_r,
                              const int* __restrict__ rp_u,
                              const ull* __restrict__ pk_r,
                              const ull* __restrict__ pk_u,
                              int2* __restrict__ combo_r,
                              int2* __restrict__ combo_u,
                              const int* __restrict__ bsum, int nbR) {
    bool isR = (int)blockIdx.x < nbR;
    const int* rp = isR ? rp_r : rp_u;
    const ull* pk = isR ? pk_r : pk_u;
    int2* combo   = isR ? combo_r : combo_u;
    int ncnt  = isR ? NR : NU;
    int b     = isR ? (int)blockIdx.x : (int)blockIdx.x - nbR;
    int i = b * 256 + threadIdx.x;
    if (i < ncnt + 1) {
        int rpv = rp[i] + bsum[blockIdx.x];
        float deg = (i < ncnt) ? (float)(pk[i] & DEG_MASK) * DEG_INV : 0.0f;
        combo[i] = make_int2(rpv, __float_as_int(deg));
    }
}

// ---- K4b: per-bucket rank + CSR entry emit -------------------------------

__global__ void emit_kernel(const ull* __restrict__ buf_r,
                            const ull* __restrict__ buf_u,
                            const unsigned* __restrict__ boff_r,
                            const unsigned* __restrict__ boff_u,
                            const int2* __restrict__ combo_r,
                            const int2* __restrict__ combo_u,
                            unsigned* __restrict__ pair_r,
                            unsigned* __restrict__ pair_u) {
    bool isR = (int)blockIdx.x < NBK;
    int j = isR ? (int)blockIdx.x : (int)blockIdx.x - NBK;
    const ull* buf = isR ? buf_r : buf_u;
    const unsigned* boff = isR ? boff_r : boff_u;
    const int2* combo  = isR ? combo_r : combo_u;
    const int2* comboO = isR ? combo_u : combo_r;
    unsigned* pair = isR ? pair_r : pair_u;
    int span = isR ? SPAN_R : SPAN_U;
    int nnode = isR ? NR : NU;
    __shared__ int rp_l[512];
    __shared__ float deg_l[512];
    __shared__ unsigned cur[512];
    int nb = j * span;
    for (int i = threadIdx.x; i < span; i += 256) {
        int node = nb + i;
        int2 c = (node < nnode) ? combo[node] : make_int2(0, 0);
        rp_l[i] = c.x;
        deg_l[i] = __int_as_float(c.y);
        cur[i] = 0;
    }
    __syncthreads();
    unsigned beg = boff[j], end = boff[j + 1];
    for (unsigned e = beg + threadIdx.x; e < end; e += 256) {
        ull rec = buf[e];
        unsigned src = (unsigned)(rec & 0x3FFFFu);
        int dlow = (int)((rec >> 18) & 511);
        float wv = __half2float(__ushort_as_half((unsigned short)(rec >> 32)));
        float dO = __int_as_float(comboO[src].y);
        float nv = wv * rsqrtf(fmaxf(deg_l[dlow] * dO, 1e-12f));
        unsigned short hb = __half_as_ushort(__float2half(nv));
        unsigned n14 = ((unsigned)hb + 1u) >> 1;
        unsigned rank = atomicAdd(&cur[dlow], 1u);
        pair[rp_l[dlow] + (int)rank] = (n14 << 18) | src;
    }
}

// ---- main propagation: one wave per destination row ----------------------
// IMODE: 0 = pure gather, 1 = rec epilogue (f32 concat init),
//        2 = usr epilogue (bf16 init from emb_h)
// pair loads are wave-uniform plain loads -> scalar path (s_load_dwordx4).

template<int IMODE>
__global__ void gather_rows(const unsigned* __restrict__ src,
                            const int2* __restrict__ combo,
                            const unsigned* __restrict__ pair,
                            unsigned* __restrict__ xout,
                            float* __restrict__ out_f,
                            const unsigned* __restrict__ prev1,
                            const unsigned* __restrict__ prev2,
                            const float* __restrict__ init_a,
                            const float* __restrict__ init_b,
                            const unsigned* __restrict__ init_h,
                            int nrows) {
    int wid  = (blockIdx.x * blockDim.x + threadIdx.x) >> 6;
    wid = __builtin_amdgcn_readfirstlane(wid);
    int lane = threadIdx.x & 63;
    if (wid >= nrows) return;

    int beg = __builtin_amdgcn_readfirstlane(combo[wid].x);
    int end = __builtin_amdgcn_readfirstlane(combo[wid + 1].x);
    float x0 = 0.f, y0 = 0.f, x1 = 0.f, y1 = 0.f;
    float x2 = 0.f, y2 = 0.f, x3 = 0.f, y3 = 0.f;

#define LOAD_EDGE(P, AX, AY)                                                  \
    {                                                                         \
        unsigned s = (P) & 0x3FFFFu;                                          \
        float n = __half2float(__ushort_as_half(                              \
                      (unsigned short)(((P) >> 18) << 1)));                   \
        unsigned v = src[(size_t)s * 64 + lane];                              \
        AX += n * __uint_as_float(v << 16);                                   \
        AY += n * __uint_as_float(v & 0xffff0000u);                           \
    }

    int e = beg;
    for (; e + 16 <= end; e += 16) {
        uint4 pa = *reinterpret_cast<const uint4*>(pair + e);
        uint4 pb = *reinterpret_cast<const uint4*>(pair + e + 4);
        uint4 pc = *reinterpret_cast<const uint4*>(pair + e + 8);
        uint4 pd = *reinterpret_cast<const uint4*>(pair + e + 12);
        LOAD_EDGE(pa.x, x0, y0) LOAD_EDGE(pa.y, x1, y1)
        LOAD_EDGE(pa.z, x2, y2) LOAD_EDGE(pa.w, x3, y3)
        LOAD_EDGE(pb.x, x0, y0) LOAD_EDGE(pb.y, x1, y1)
        LOAD_EDGE(pb.z, x2, y2) LOAD_EDGE(pb.w, x3, y3)
        LOAD_EDGE(pc.x, x0, y0) LOAD_EDGE(pc.y, x1, y1)
        LOAD_EDGE(pc.z, x2, y2) LOAD_EDGE(pc.w, x3, y3)
        LOAD_EDGE(pd.x, x0, y0) LOAD_EDGE(pd.y, x1, y1)
        LOAD_EDGE(pd.z, x2, y2) LOAD_EDGE(pd.w, x3, y3)
    }
    for (; e < end; e += 4) {   // rows padded to multiple of 4
        uint4 pa = *reinterpret_cast<const uint4*>(pair + e);
        LOAD_EDGE(pa.x, x0, y0) LOAD_EDGE(pa.y, x1, y1)
        LOAD_EDGE(pa.z, x2, y2) LOAD_EDGE(pa.w, x3, y3)
    }
#undef LOAD_EDGE

    x0 = (x0 + x1) + (x2 + x3);
    y0 = (y0 + y1) + (y2 + y3);

    size_t xo = (size_t)wid * 64 + lane;
    if (xout) __builtin_nontemporal_store(pack_bf16x2(x0, y0), &xout[xo]);

    if (out_f) {
        size_t o = (size_t)wid * D + lane * 2;
        float bx, by;
        if constexpr (IMODE == 1) {
            float2v b = (lane < 16)
                ? __builtin_nontemporal_load(reinterpret_cast<const float2v*>(
                      init_a + (size_t)wid * EMB + lane * 2))
                : __builtin_nontemporal_load(reinterpret_cast<const float2v*>(
                      init_b + (size_t)wid * RDIM + (lane * 2 - EMB)));
            bx = b[0]; by = b[1];
        } else {
            unsigned hv = __builtin_nontemporal_load(&init_h[xo]);
            bx = blo(hv); by = bhi(hv);
        }
        unsigned v1 = __builtin_nontemporal_load(&prev1[xo]);
        unsigned v2 = __builtin_nontemporal_load(&prev2[xo]);
        float lo = bx + blo(v1) + blo(v2) + x0;
        float hi = by + bhi(v1) + bhi(v2) + y0;
        float2v ov = {ALPHA * lo, ALPHA * hi};
        __builtin_nontemporal_store(ov, reinterpret_cast<float2v*>(out_f + o));
    }
}

// fallback-mode variants
__global__ void gather_rows_acc(const unsigned* __restrict__ src,
                                const int2* __restrict__ combo,
                                const unsigned* __restrict__ pair,
                                unsigned* __restrict__ xout,
                                float* __restrict__ out_f,
                                int nrows) {
    int wid  = (blockIdx.x * blockDim.x + threadIdx.x) >> 6;
    wid = __builtin_amdgcn_readfirstlane(wid);
    int lane = threadIdx.x & 63;
    if (wid >= nrows) return;
    int beg = __builtin_amdgcn_readfirstlane(combo[wid].x);
    int end = __builtin_amdgcn_readfirstlane(combo[wid + 1].x);
    float x0 = 0.f, y0 = 0.f;
    for (int e = beg; e < end; ++e) {
        unsigned P = pair[e];
        unsigned s = P & 0x3FFFFu;
        float n = __half2float(__ushort_as_half((unsigned short)((P >> 18) << 1)));
        unsigned v = src[(size_t)s * 64 + lane];
        x0 += n * blo(v); y0 += n * bhi(v);
    }
    size_t xo = (size_t)wid * 64 + lane;
    if (xout) xout[xo] = pack_bf16x2(x0, y0);
    size_t o = (size_t)wid * D + lane * 2;
    float2 ov = *reinterpret_cast<float2*>(out_f + o);
    ov.x += ALPHA * x0; ov.y += ALPHA * y0;
    *reinterpret_cast<float2*>(out_f + o) = ov;
}

__global__ void init_out_kernel(const float* __restrict__ usr_emb,
                                const float* __restrict__ rcp_emb,
                                const float* __restrict__ rfeat,
                                float* __restrict__ out) {
    long long i = blockIdx.x * (long long)blockDim.x + threadIdx.x;
    const long long UD = (long long)NU * D;
    const long long RD = (long long)NR * D;
    if (i < UD) {
        out[i] = ALPHA * usr_emb[i];
    } else if (i < UD + RD) {
        long long j = i - UD;
        int r = (int)(j >> 7);
        int d = (int)(j & 127);
        float v = (d < EMB) ? rcp_emb[(long long)r * EMB + d]
                            : rfeat[(long long)r * RDIM + (d - EMB)];
        out[i] = ALPHA * v;
    }
}

// ---- launch --------------------------------------------------------------

extern "C" void kernel_launch(void* const* d_in, const int* in_sizes, int n_in,
                              void* d_out, int out_size, void* d_ws, size_t ws_size,
                              hipStream_t stream) {
    const float* usr_emb = (const float*)d_in[0];
    const float* rcp_emb = (const float*)d_in[1];
    const float* rfeat   = (const float*)d_in[2];
    const float* w       = (const float*)d_in[3];
    const int*   ui      = (const int*)d_in[4];
    const int*   ri      = (const int*)d_in[5];

    float* out     = (float*)d_out;
    float* usr_out = out;
    float* rec_out = out + (size_t)NU * D;

    char* p0 = (char*)d_ws;
    char* p = p0;
    auto take = [&](size_t bytes) -> char* {
        char* q = p;
        p += (bytes + 255) & ~(size_t)255;
        return q;
    };

    const int PR_SLOTS = NE + 3 * NR + 16;
    const int PU_SLOTS = NE + 3 * NU + 16;

    unsigned* pair_r = (unsigned*)take((size_t)PR_SLOTS * 4);
    unsigned* pair_u = (unsigned*)take((size_t)PU_SLOTS * 4);
    char*     zero_end = p;
    ull*      pk_u    = (ull*)take((size_t)NU * 8);
    ull*      pk_r    = (ull*)take((size_t)NR * 8);
    int*      rp_r    = (int*)take((size_t)(NR + 1) * 4);
    int*      rp_u    = (int*)take((size_t)(NU + 1) * 4);
    int2*     combo_r = (int2*)take((size_t)(NR + 1) * 8);
    int2*     combo_u = (int2*)take((size_t)(NU + 1) * 8);
    int*      bsum    = (int*)take(4096 * 4);
    unsigned* btot    = (unsigned*)take((size_t)2 * NBK * 4);
    unsigned* boff_r  = (unsigned*)take((size_t)(NBK + 1) * 4);
    unsigned* boff_u  = (unsigned*)take((size_t)(NBK + 1) * 4);
    unsigned* emb_h   = (unsigned*)take((size_t)NU * 64 * 4);

    const size_t xr_b = (size_t)NR * 64 * 4;
    const size_t xu_b = (size_t)NU * 64 * 4;
    size_t used_head = (size_t)(p - p0);
    bool deferred = (ws_size >= used_head + 3 * ((xr_b + 255) & ~(size_t)255)
                                         + 2 * ((xu_b + 255) & ~(size_t)255));

    unsigned *xr0, *xr1, *xr2, *xu0, *xu1;
    if (deferred) {
        xr0 = (unsigned*)take(xr_b); xr1 = (unsigned*)take(xr_b); xr2 = (unsigned*)take(xr_b);
        xu0 = (unsigned*)take(xu_b); xu1 = (unsigned*)take(xu_b);
    } else {
        xr0 = xr1 = xr2 = (unsigned*)take(xr_b);
        xu0 = xu1 = (unsigned*)take(xu_b);
    }

    ull*      buf_r  = (ull*)xr0;
    ull*      buf_u  = buf_r + NE;
    unsigned* hist_r = (unsigned*)(buf_u + NE);
    unsigned* hist_u = hist_r + (size_t)NBK * B1;

    const int B = 256;

    hipMemsetAsync(pair_r, 0, (size_t)(zero_end - (char*)pair_r), stream);

    hist_kernel<<<B1 + CB, B, 0, stream>>>(ui, ri, hist_u, hist_r,
                                           (const float4*)usr_emb, (uint4*)emb_h);
    scan_hist<<<2 * NBK, 512, 0, stream>>>(hist_r, hist_u, btot);
    scan_btot<<<2, 512, 0, stream>>>(btot, boff_r, boff_u);
    scatter_kernel<<<B1, B, 0, stream>>>(ui, ri, w, hist_u, hist_r,
                                         boff_u, boff_r, buf_u, buf_r);
    count_kernel<<<2 * NBK, B, 0, stream>>>(buf_r, buf_u, boff_r, boff_u, pk_r, pk_u);

    const int nbR = (NR + 1 + 255) / 256;
    const int nbU = (NU + 1 + 255) / 256;
    scan_block_both<<<nbR + nbU, 256, 0, stream>>>(pk_r, pk_u, rp_r, rp_u, bsum, nbR);
    scan_bsum2<<<2, 1024, 0, stream>>>(bsum, nbR, nbU);
    finalize_both<<<nbR + nbU, 256, 0, stream>>>(rp_r, rp_u, pk_r, pk_u,
                                                 combo_r, combo_u, bsum, nbR);
    emit_kernel<<<2 * NBK, B, 0, stream>>>(buf_r, buf_u, boff_r, boff_u,
                                           combo_r, combo_u, pair_r, pair_u);

    const int GB_R = (NR * 64 + B - 1) / B;
    const int GB_U = (NU * 64 + B - 1) / B;

    if (deferred) {
        gather_rows<0><<<GB_R, B, 0, stream>>>(emb_h, combo_r, pair_r, xr0,
                                               nullptr, nullptr, nullptr, nullptr, nullptr, nullptr, NR);
        gather_rows<0><<<GB_U, B, 0, stream>>>(xr0, combo_u, pair_u, xu0,
                                               nullptr, nullptr, nullptr, nullptr, nullptr, nullptr, NU);
        gather_rows<0><<<GB_R, B, 0, stream>>>(xu0, combo_r, pair_r, xr1,
                                               nullptr, nullptr, nullptr, nullptr, nullptr, nullptr, NR);
        gather_rows<0><<<GB_U, B, 0, stream>>>(xr1, combo_u, pair_u, xu1,
                                               nullptr, nullptr, nullptr, nullptr, nullptr, nullptr, NU);
        gather_rows<1><<<GB_R, B, 0, stream>>>(xu1, combo_r, pair_r, xr2,
                                               rec_out, xr0, xr1, rcp_emb, rfeat, nullptr, NR);
        gather_rows<2><<<GB_U, B, 0, stream>>>(xr2, combo_u, pair_u, nullptr,
                                               usr_out, xu0, xu1, nullptr, nullptr, emb_h, NU);
    } else {
        long long tot = (long long)(NU + NR) * D;
        init_out_kernel<<<(int)((tot + B - 1) / B), B, 0, stream>>>(usr_emb, rcp_emb, rfeat, out);
        gather_rows_acc<<<GB_R, B, 0, stream>>>(emb_h, combo_r, pair_r, xr0, rec_out, NR);
        gather_rows_acc<<<GB_U, B, 0, stream>>>(xr0, combo_u, pair_u, xu0, usr_out, NU);
        gather_rows_acc<<<GB_R, B, 0, stream>>>(xu0, combo_r, pair_r, xr0, rec_out, NR);
        gather_rows_acc<<<GB_U, B, 0, stream>>>(xr0, combo_u, pair_u, xu0, usr_out, NU);
        gather_rows_acc<<<GB_R, B, 0, stream>>>(xu0, combo_r, pair_r, xr0, rec_out, NR);
        gather_rows_acc<<<GB_U, B, 0, stream>>>(xr0, combo_u, pair_u, nullptr, usr_out, NU);
    }
}

// Round 12
// 530.395 us; speedup vs baseline: 1.0231x; 1.0231x over previous
//
#include <hip/hip_runtime.h>
#include <hip/hip_fp16.h>

// RecLGN: 3-layer weighted LightGCN on bipartite user-recipe graph.
// v12 == v10 (revert of v11's scalar-pair experiment, which regressed):
// pad-to-4 CSR rows (16/8/4 gather loop), nontemporal streaming
// loads/stores (keep L2 for gather sources), pass-6 init from bf16 emb.
// Atomic-free bucket-sort CSR build. Entries: norm_e5m9[31:18]|idx[17:0].

typedef unsigned long long ull;
typedef unsigned uint4v __attribute__((ext_vector_type(4)));
typedef float float2v __attribute__((ext_vector_type(2)));

constexpr int NU   = 100000;
constexpr int NR   = 200000;
constexpr int EMB  = 32;
constexpr int RDIM = 96;
constexpr int D    = 128;
constexpr int NE   = 1500000;
constexpr float ALPHA = 0.25f;  // 1/(NUM_LAYERS+1)

constexpr ull DEG_MASK = (1ULL << 44) - 1;
constexpr float DEG_SCALE = 1048576.0f;   // 2^20
constexpr float DEG_INV   = 1.0f / 1048576.0f;

// bucket decomposition
constexpr int NBK    = 391;
constexpr int SPAN_R = 512;   // r >> 9
constexpr int SPAN_U = 256;   // u >> 8
constexpr int EPB    = 4096;
constexpr int B1     = (NE + EPB - 1) / EPB;
constexpr int CB     = (NU * D / 16 + 255) / 256;

// ---- bf16 helpers --------------------------------------------------------

__device__ __forceinline__ unsigned pack_bf16x2(float x, float y) {
    unsigned ux = __float_as_uint(x);
    unsigned uy = __float_as_uint(y);
    ux += 0x7fffu + ((ux >> 16) & 1u);
    uy += 0x7fffu + ((uy >> 16) & 1u);
    return (ux >> 16) | (uy & 0xffff0000u);
}

__device__ __forceinline__ float blo(unsigned u) { return __uint_as_float(u << 16); }
__device__ __forceinline__ float bhi(unsigned u) { return __uint_as_float(u & 0xffff0000u); }

// ---- K1: per-block LDS histograms (+ usr_emb bf16 convert) ---------------

__global__ void hist_kernel(const int* __restrict__ ui,
                            const int* __restrict__ ri,
                            unsigned* __restrict__ hist_u,
                            unsigned* __restrict__ hist_r,
                            const float4* __restrict__ usr_emb4,
                            uint4* __restrict__ emb_h4) {
    if ((int)blockIdx.x >= B1) {
        int t = ((int)blockIdx.x - B1) * 256 + threadIdx.x;
        if (t < NU * D / 16) {
            int base = t * 4;
            float4 a = usr_emb4[base], b = usr_emb4[base + 1];
            float4 c = usr_emb4[base + 2], d = usr_emb4[base + 3];
            uint4 o0 = {pack_bf16x2(a.x, a.y), pack_bf16x2(a.z, a.w),
                        pack_bf16x2(b.x, b.y), pack_bf16x2(b.z, b.w)};
            uint4 o1 = {pack_bf16x2(c.x, c.y), pack_bf16x2(c.z, c.w),
                        pack_bf16x2(d.x, d.y), pack_bf16x2(d.z, d.w)};
            emb_h4[t * 2]     = o0;
            emb_h4[t * 2 + 1] = o1;
        }
        return;
    }
    __shared__ unsigned hu[NBK], hr[NBK];
    for (int j = threadIdx.x; j < NBK; j += 256) { hu[j] = 0; hr[j] = 0; }
    __syncthreads();
    int base = blockIdx.x * EPB;
    for (int k = 0; k < 16; ++k) {
        int i = base + k * 256 + threadIdx.x;
        if (i < NE) {
            atomicAdd(&hu[ui[i] >> 8], 1u);
            atomicAdd(&hr[ri[i] >> 9], 1u);
        }
    }
    __syncthreads();
    for (int j = threadIdx.x; j < NBK; j += 256) {
        hist_u[j * B1 + blockIdx.x] = hu[j];
        hist_r[j * B1 + blockIdx.x] = hr[j];
    }
}

// ---- K2a/K2b: bucket scans ------------------------------------------------

__global__ void scan_hist(unsigned* __restrict__ hist_r,
                          unsigned* __restrict__ hist_u,
                          unsigned* __restrict__ btot) {
    __shared__ unsigned tmp[512];
    bool isR = (int)blockIdx.x < NBK;
    int j = isR ? (int)blockIdx.x : (int)blockIdx.x - NBK;
    unsigned* h = (isR ? hist_r : hist_u) + (size_t)j * B1;
    int i = threadIdx.x;
    unsigned v = (i < B1) ? h[i] : 0;
    tmp[i] = v;
    __syncthreads();
    for (int o = 1; o < 512; o <<= 1) {
        unsigned t = (i >= o) ? tmp[i - o] : 0;
        __syncthreads();
        tmp[i] += t;
        __syncthreads();
    }
    if (i < B1) h[i] = tmp[i] - v;
    if (i == 511) btot[blockIdx.x] = tmp[511];
}

__global__ void scan_btot(const unsigned* __restrict__ btot,
                          unsigned* __restrict__ boff_r,
                          unsigned* __restrict__ boff_u) {
    __shared__ unsigned tmp[512];
    bool isR = (blockIdx.x == 0);
    unsigned* boff = isR ? boff_r : boff_u;
    int i = threadIdx.x;
    unsigned v = (i < NBK) ? btot[(isR ? 0 : NBK) + i] : 0;
    tmp[i] = v;
    __syncthreads();
    for (int o = 1; o < 512; o <<= 1) {
        unsigned t = (i >= o) ? tmp[i - o] : 0;
        __syncthreads();
        tmp[i] += t;
        __syncthreads();
    }
    if (i < NBK) boff[i] = tmp[i] - v;
    if (i == 0) boff[NBK] = tmp[511];
}

// ---- K3: scatter into bucket regions (LDS cursors) -----------------------

__global__ void scatter_kernel(const int* __restrict__ ui,
                               const int* __restrict__ ri,
                               const float* __restrict__ w,
                               const unsigned* __restrict__ hist_u,
                               const unsigned* __restrict__ hist_r,
                               const unsigned* __restrict__ boff_u,
                               const unsigned* __restrict__ boff_r,
                               ull* __restrict__ buf_u,
                               ull* __restrict__ buf_r) {
    __shared__ unsigned cu[NBK], cr[NBK];
    for (int j = threadIdx.x; j < NBK; j += 256) {
        cu[j] = boff_u[j] + hist_u[j * B1 + blockIdx.x];
        cr[j] = boff_r[j] + hist_r[j * B1 + blockIdx.x];
    }
    __syncthreads();
    int base = blockIdx.x * EPB;
    for (int k = 0; k < 16; ++k) {
        int i = base + k * 256 + threadIdx.x;
        if (i < NE) {
            int u = ui[i], r = ri[i];
            ull wh = (ull)__half_as_ushort(__float2half(w[i]));
            ull rec_r = (ull)(unsigned)u | ((ull)(r & 511) << 18) | (wh << 32);
            ull rec_u = (ull)(unsigned)r | ((ull)(u & 255) << 18) | (wh << 32);
            unsigned sr = atomicAdd(&cr[r >> 9], 1u);
            unsigned su = atomicAdd(&cu[u >> 8], 1u);
            buf_r[sr] = rec_r;
            buf_u[su] = rec_u;
        }
    }
}

// ---- K4a: per-bucket count + weighted degree -> pk -----------------------

__global__ void count_kernel(const ull* __restrict__ buf_r,
                             const ull* __restrict__ buf_u,
                             const unsigned* __restrict__ boff_r,
                             const unsigned* __restrict__ boff_u,
                             ull* __restrict__ pk_r,
                             ull* __restrict__ pk_u) {
    bool isR = (int)blockIdx.x < NBK;
    int j = isR ? (int)blockIdx.x : (int)blockIdx.x - NBK;
    const ull* buf = isR ? buf_r : buf_u;
    const unsigned* boff = isR ? boff_r : boff_u;
    ull* pk = isR ? pk_r : pk_u;
    int span = isR ? SPAN_R : SPAN_U;
    int nnode = isR ? NR : NU;
    __shared__ unsigned cnt[512], wfx[512];
    for (int i = threadIdx.x; i < span; i += 256) { cnt[i] = 0; wfx[i] = 0; }
    __syncthreads();
    unsigned beg = boff[j], end = boff[j + 1];
    for (unsigned e = beg + threadIdx.x; e < end; e += 256) {
        ull rec = buf[e];
        int dlow = (int)((rec >> 18) & 511);
        float wv = __half2float(__ushort_as_half((unsigned short)(rec >> 32)));
        atomicAdd(&cnt[dlow], 1u);
        atomicAdd(&wfx[dlow], (unsigned)(wv * DEG_SCALE + 0.5f));
    }
    __syncthreads();
    int nb = j * span;
    for (int i = threadIdx.x; i < span; i += 256) {
        int node = nb + i;
        if (node < nnode) pk[node] = ((ull)cnt[i] << 44) | (ull)wfx[i];
    }
}

// ---- CSR scans (pad rows to multiple of 4) -------------------------------

__global__ void scan_block_both(const ull* __restrict__ pk_r,
                                const ull* __restrict__ pk_u,
                                int* __restrict__ rp_r,
                                int* __restrict__ rp_u,
                                int* __restrict__ bsum, int nbR) {
    __shared__ int tmp[256];
    bool isR = (int)blockIdx.x < nbR;
    const ull* pk = isR ? pk_r : pk_u;
    int* excl = isR ? rp_r : rp_u;
    int ncnt  = isR ? NR : NU;
    int b     = isR ? (int)blockIdx.x : (int)blockIdx.x - nbR;
    int nscan = ncnt + 1;
    int i = b * 256 + threadIdx.x;
    int v = 0;
    if (i < ncnt) v = ((int)(pk[i] >> 44) + 3) & ~3;   // pad to mult of 4
    tmp[threadIdx.x] = v;
    __syncthreads();
    for (int off = 1; off < 256; off <<= 1) {
        int t = (threadIdx.x >= off) ? tmp[threadIdx.x - off] : 0;
        __syncthreads();
        tmp[threadIdx.x] += t;
        __syncthreads();
    }
    if (i < nscan) excl[i] = tmp[threadIdx.x] - v;
    if (threadIdx.x == 255) bsum[blockIdx.x] = tmp[255];
}

__global__ void scan_bsum2(int* __restrict__ bsum, int nbR, int nbU) {
    __shared__ int tmp[1024];
    int off = (blockIdx.x == 0) ? 0 : nbR;
    int nb  = (blockIdx.x == 0) ? nbR : nbU;
    int i = threadIdx.x;
    int v = (i < nb) ? bsum[off + i] : 0;
    tmp[i] = v;
    __syncthreads();
    for (int o = 1; o < 1024; o <<= 1) {
        int t = (i >= o) ? tmp[i - o] : 0;
        __syncthreads();
        tmp[i] += t;
        __syncthreads();
    }
    if (i < nb) bsum[off + i] = tmp[i] - v;
}

__global__ void finalize_both(const int* __restrict__ rp_r,
                              const int* __restrict__ rp_u,
                              const ull* __restrict__ pk_r,
                              const ull* __restrict__ pk_u,
                              int2* __restrict__ combo_r,
                              int2* __restrict__ combo_u,
                              const int* __restrict__ bsum, int nbR) {
    bool isR = (int)blockIdx.x < nbR;
    const int* rp = isR ? rp_r : rp_u;
    const ull* pk = isR ? pk_r : pk_u;
    int2* combo   = isR ? combo_r : combo_u;
    int ncnt  = isR ? NR : NU;
    int b     = isR ? (int)blockIdx.x : (int)blockIdx.x - nbR;
    int i = b * 256 + threadIdx.x;
    if (i < ncnt + 1) {
        int rpv = rp[i] + bsum[blockIdx.x];
        float deg = (i < ncnt) ? (float)(pk[i] & DEG_MASK) * DEG_INV : 0.0f;
        combo[i] = make_int2(rpv, __float_as_int(deg));
    }
}

// ---- K4b: per-bucket rank + CSR entry emit -------------------------------

__global__ void emit_kernel(const ull* __restrict__ buf_r,
                            const ull* __restrict__ buf_u,
                            const unsigned* __restrict__ boff_r,
                            const unsigned* __restrict__ boff_u,
                            const int2* __restrict__ combo_r,
                            const int2* __restrict__ combo_u,
                            unsigned* __restrict__ pair_r,
                            unsigned* __restrict__ pair_u) {
    bool isR = (int)blockIdx.x < NBK;
    int j = isR ? (int)blockIdx.x : (int)blockIdx.x - NBK;
    const ull* buf = isR ? buf_r : buf_u;
    const unsigned* boff = isR ? boff_r : boff_u;
    const int2* combo  = isR ? combo_r : combo_u;
    const int2* comboO = isR ? combo_u : combo_r;
    unsigned* pair = isR ? pair_r : pair_u;
    int span = isR ? SPAN_R : SPAN_U;
    int nnode = isR ? NR : NU;
    __shared__ int rp_l[512];
    __shared__ float deg_l[512];
    __shared__ unsigned cur[512];
    int nb = j * span;
    for (int i = threadIdx.x; i < span; i += 256) {
        int node = nb + i;
        int2 c = (node < nnode) ? combo[node] : make_int2(0, 0);
        rp_l[i] = c.x;
        deg_l[i] = __int_as_float(c.y);
        cur[i] = 0;
    }
    __syncthreads();
    unsigned beg = boff[j], end = boff[j + 1];
    for (unsigned e = beg + threadIdx.x; e < end; e += 256) {
        ull rec = buf[e];
        unsigned src = (unsigned)(rec & 0x3FFFFu);
        int dlow = (int)((rec >> 18) & 511);
        float wv = __half2float(__ushort_as_half((unsigned short)(rec >> 32)));
        float dO = __int_as_float(comboO[src].y);
        float nv = wv * rsqrtf(fmaxf(deg_l[dlow] * dO, 1e-12f));
        unsigned short hb = __half_as_ushort(__float2half(nv));
        unsigned n14 = ((unsigned)hb + 1u) >> 1;
        unsigned rank = atomicAdd(&cur[dlow], 1u);
        pair[rp_l[dlow] + (int)rank] = (n14 << 18) | src;
    }
}

// ---- main propagation: one wave per destination row ----------------------
// IMODE: 0 = pure gather, 1 = rec epilogue (f32 concat init),
//        2 = usr epilogue (bf16 init from emb_h)

template<int IMODE>
__global__ void gather_rows(const unsigned* __restrict__ src,
                            const int2* __restrict__ combo,
                            const unsigned* __restrict__ pair,
                            unsigned* __restrict__ xout,
                            float* __restrict__ out_f,
                            const unsigned* __restrict__ prev1,
                            const unsigned* __restrict__ prev2,
                            const float* __restrict__ init_a,
                            const float* __restrict__ init_b,
                            const unsigned* __restrict__ init_h,
                            int nrows) {
    int wid  = (blockIdx.x * blockDim.x + threadIdx.x) >> 6;
    wid = __builtin_amdgcn_readfirstlane(wid);
    int lane = threadIdx.x & 63;
    if (wid >= nrows) return;

    int beg = __builtin_amdgcn_readfirstlane(combo[wid].x);
    int end = __builtin_amdgcn_readfirstlane(combo[wid + 1].x);
    float x0 = 0.f, y0 = 0.f, x1 = 0.f, y1 = 0.f;
    float x2 = 0.f, y2 = 0.f, x3 = 0.f, y3 = 0.f;

#define PLOAD(E) __builtin_nontemporal_load(reinterpret_cast<const uint4v*>(pair + (E)))
#define LOAD_EDGE(P, AX, AY)                                                  \
    {                                                                         \
        unsigned s = (P) & 0x3FFFFu;                                          \
        float n = __half2float(__ushort_as_half(                              \
                      (unsigned short)(((P) >> 18) << 1)));                   \
        unsigned v = src[(size_t)s * 64 + lane];                              \
        AX += n * __uint_as_float(v << 16);                                   \
        AY += n * __uint_as_float(v & 0xffff0000u);                           \
    }

    int e = beg;
    for (; e + 16 <= end; e += 16) {
        uint4v pa = PLOAD(e), pb = PLOAD(e + 4), pc = PLOAD(e + 8), pd = PLOAD(e + 12);
        LOAD_EDGE(pa[0], x0, y0) LOAD_EDGE(pa[1], x1, y1)
        LOAD_EDGE(pa[2], x2, y2) LOAD_EDGE(pa[3], x3, y3)
        LOAD_EDGE(pb[0], x0, y0) LOAD_EDGE(pb[1], x1, y1)
        LOAD_EDGE(pb[2], x2, y2) LOAD_EDGE(pb[3], x3, y3)
        LOAD_EDGE(pc[0], x0, y0) LOAD_EDGE(pc[1], x1, y1)
        LOAD_EDGE(pc[2], x2, y2) LOAD_EDGE(pc[3], x3, y3)
        LOAD_EDGE(pd[0], x0, y0) LOAD_EDGE(pd[1], x1, y1)
        LOAD_EDGE(pd[2], x2, y2) LOAD_EDGE(pd[3], x3, y3)
    }
    for (; e + 8 <= end; e += 8) {
        uint4v pa = PLOAD(e), pb = PLOAD(e + 4);
        LOAD_EDGE(pa[0], x0, y0) LOAD_EDGE(pa[1], x1, y1)
        LOAD_EDGE(pa[2], x2, y2) LOAD_EDGE(pa[3], x3, y3)
        LOAD_EDGE(pb[0], x0, y0) LOAD_EDGE(pb[1], x1, y1)
        LOAD_EDGE(pb[2], x2, y2) LOAD_EDGE(pb[3], x3, y3)
    }
    if (e < end) {   // exactly 4 remain (rows padded to multiple of 4)
        uint4v pa = PLOAD(e);
        LOAD_EDGE(pa[0], x0, y0) LOAD_EDGE(pa[1], x1, y1)
        LOAD_EDGE(pa[2], x2, y2) LOAD_EDGE(pa[3], x3, y3)
    }
#undef LOAD_EDGE
#undef PLOAD

    x0 = (x0 + x1) + (x2 + x3);
    y0 = (y0 + y1) + (y2 + y3);

    size_t xo = (size_t)wid * 64 + lane;
    if (xout) __builtin_nontemporal_store(pack_bf16x2(x0, y0), &xout[xo]);

    if (out_f) {
        size_t o = (size_t)wid * D + lane * 2;
        float bx, by;
        if constexpr (IMODE == 1) {
            float2v b = (lane < 16)
                ? __builtin_nontemporal_load(reinterpret_cast<const float2v*>(
                      init_a + (size_t)wid * EMB + lane * 2))
                : __builtin_nontemporal_load(reinterpret_cast<const float2v*>(
                      init_b + (size_t)wid * RDIM + (lane * 2 - EMB)));
            bx = b[0]; by = b[1];
        } else {
            unsigned hv = __builtin_nontemporal_load(&init_h[xo]);
            bx = blo(hv); by = bhi(hv);
        }
        unsigned v1 = __builtin_nontemporal_load(&prev1[xo]);
        unsigned v2 = __builtin_nontemporal_load(&prev2[xo]);
        float lo = bx + blo(v1) + blo(v2) + x0;
        float hi = by + bhi(v1) + bhi(v2) + y0;
        float2v ov = {ALPHA * lo, ALPHA * hi};
        __builtin_nontemporal_store(ov, reinterpret_cast<float2v*>(out_f + o));
    }
}

// fallback-mode variants
__global__ void gather_rows_acc(const unsigned* __restrict__ src,
                                const int2* __restrict__ combo,
                                const unsigned* __restrict__ pair,
                                unsigned* __restrict__ xout,
                                float* __restrict__ out_f,
                                int nrows) {
    int wid  = (blockIdx.x * blockDim.x + threadIdx.x) >> 6;
    wid = __builtin_amdgcn_readfirstlane(wid);
    int lane = threadIdx.x & 63;
    if (wid >= nrows) return;
    int beg = __builtin_amdgcn_readfirstlane(combo[wid].x);
    int end = __builtin_amdgcn_readfirstlane(combo[wid + 1].x);
    float x0 = 0.f, y0 = 0.f;
    for (int e = beg; e < end; ++e) {
        unsigned P = pair[e];
        unsigned s = P & 0x3FFFFu;
        float n = __half2float(__ushort_as_half((unsigned short)((P >> 18) << 1)));
        unsigned v = src[(size_t)s * 64 + lane];
        x0 += n * blo(v); y0 += n * bhi(v);
    }
    size_t xo = (size_t)wid * 64 + lane;
    if (xout) xout[xo] = pack_bf16x2(x0, y0);
    size_t o = (size_t)wid * D + lane * 2;
    float2 ov = *reinterpret_cast<float2*>(out_f + o);
    ov.x += ALPHA * x0; ov.y += ALPHA * y0;
    *reinterpret_cast<float2*>(out_f + o) = ov;
}

__global__ void init_out_kernel(const float* __restrict__ usr_emb,
                                const float* __restrict__ rcp_emb,
                                const float* __restrict__ rfeat,
                                float* __restrict__ out) {
    long long i = blockIdx.x * (long long)blockDim.x + threadIdx.x;
    const long long UD = (long long)NU * D;
    const long long RD = (long long)NR * D;
    if (i < UD) {
        out[i] = ALPHA * usr_emb[i];
    } else if (i < UD + RD) {
        long long j = i - UD;
        int r = (int)(j >> 7);
        int d = (int)(j & 127);
        float v = (d < EMB) ? rcp_emb[(long long)r * EMB + d]
                            : rfeat[(long long)r * RDIM + (d - EMB)];
        out[i] = ALPHA * v;
    }
}

// ---- launch --------------------------------------------------------------

extern "C" void kernel_launch(void* const* d_in, const int* in_sizes, int n_in,
                              void* d_out, int out_size, void* d_ws, size_t ws_size,
                              hipStream_t stream) {
    const float* usr_emb = (const float*)d_in[0];
    const float* rcp_emb = (const float*)d_in[1];
    const float* rfeat   = (const float*)d_in[2];
    const float* w       = (const float*)d_in[3];
    const int*   ui      = (const int*)d_in[4];
    const int*   ri      = (const int*)d_in[5];

    float* out     = (float*)d_out;
    float* usr_out = out;
    float* rec_out = out + (size_t)NU * D;

    char* p0 = (char*)d_ws;
    char* p = p0;
    auto take = [&](size_t bytes) -> char* {
        char* q = p;
        p += (bytes + 255) & ~(size_t)255;
        return q;
    };

    const int PR_SLOTS = NE + 3 * NR + 16;
    const int PU_SLOTS = NE + 3 * NU + 16;

    // memset region: pair arrays (pad slots must read as norm=0)
    unsigned* pair_r = (unsigned*)take((size_t)PR_SLOTS * 4);
    unsigned* pair_u = (unsigned*)take((size_t)PU_SLOTS * 4);
    char*     zero_end = p;
    // fully-overwritten region
    ull*      pk_u    = (ull*)take((size_t)NU * 8);
    ull*      pk_r    = (ull*)take((size_t)NR * 8);
    int*      rp_r    = (int*)take((size_t)(NR + 1) * 4);
    int*      rp_u    = (int*)take((size_t)(NU + 1) * 4);
    int2*     combo_r = (int2*)take((size_t)(NR + 1) * 8);
    int2*     combo_u = (int2*)take((size_t)(NU + 1) * 8);
    int*      bsum    = (int*)take(4096 * 4);
    unsigned* btot    = (unsigned*)take((size_t)2 * NBK * 4);
    unsigned* boff_r  = (unsigned*)take((size_t)(NBK + 1) * 4);
    unsigned* boff_u  = (unsigned*)take((size_t)(NBK + 1) * 4);
    unsigned* emb_h   = (unsigned*)take((size_t)NU * 64 * 4);

    const size_t xr_b = (size_t)NR * 64 * 4;
    const size_t xu_b = (size_t)NU * 64 * 4;
    size_t used_head = (size_t)(p - p0);
    bool deferred = (ws_size >= used_head + 3 * ((xr_b + 255) & ~(size_t)255)
                                         + 2 * ((xu_b + 255) & ~(size_t)255));

    unsigned *xr0, *xr1, *xr2, *xu0, *xu1;
    if (deferred) {
        xr0 = (unsigned*)take(xr_b); xr1 = (unsigned*)take(xr_b); xr2 = (unsigned*)take(xr_b);
        xu0 = (unsigned*)take(xu_b); xu1 = (unsigned*)take(xu_b);
    } else {
        xr0 = xr1 = xr2 = (unsigned*)take(xr_b);
        xu0 = xu1 = (unsigned*)take(xu_b);
    }

    // bucket-sort scratch aliased into xr0 (dead until first gather)
    ull*      buf_r  = (ull*)xr0;
    ull*      buf_u  = buf_r + NE;
    unsigned* hist_r = (unsigned*)(buf_u + NE);
    unsigned* hist_u = hist_r + (size_t)NBK * B1;

    const int B = 256;

    hipMemsetAsync(pair_r, 0, (size_t)(zero_end - (char*)pair_r), stream);

    hist_kernel<<<B1 + CB, B, 0, stream>>>(ui, ri, hist_u, hist_r,
                                           (const float4*)usr_emb, (uint4*)emb_h);
    scan_hist<<<2 * NBK, 512, 0, stream>>>(hist_r, hist_u, btot);
    scan_btot<<<2, 512, 0, stream>>>(btot, boff_r, boff_u);
    scatter_kernel<<<B1, B, 0, stream>>>(ui, ri, w, hist_u, hist_r,
                                         boff_u, boff_r, buf_u, buf_r);
    count_kernel<<<2 * NBK, B, 0, stream>>>(buf_r, buf_u, boff_r, boff_u, pk_r, pk_u);

    const int nbR = (NR + 1 + 255) / 256;
    const int nbU = (NU + 1 + 255) / 256;
    scan_block_both<<<nbR + nbU, 256, 0, stream>>>(pk_r, pk_u, rp_r, rp_u, bsum, nbR);
    scan_bsum2<<<2, 1024, 0, stream>>>(bsum, nbR, nbU);
    finalize_both<<<nbR + nbU, 256, 0, stream>>>(rp_r, rp_u, pk_r, pk_u,
                                                 combo_r, combo_u, bsum, nbR);
    emit_kernel<<<2 * NBK, B, 0, stream>>>(buf_r, buf_u, boff_r, boff_u,
                                           combo_r, combo_u, pair_r, pair_u);

    const int GB_R = (NR * 64 + B - 1) / B;
    const int GB_U = (NU * 64 + B - 1) / B;

    if (deferred) {
        gather_rows<0><<<GB_R, B, 0, stream>>>(emb_h, combo_r, pair_r, xr0,
                                               nullptr, nullptr, nullptr, nullptr, nullptr, nullptr, NR);
        gather_rows<0><<<GB_U, B, 0, stream>>>(xr0, combo_u, pair_u, xu0,
                                               nullptr, nullptr, nullptr, nullptr, nullptr, nullptr, NU);
        gather_rows<0><<<GB_R, B, 0, stream>>>(xu0, combo_r, pair_r, xr1,
                                               nullptr, nullptr, nullptr, nullptr, nullptr, nullptr, NR);
        gather_rows<0><<<GB_U, B, 0, stream>>>(xr1, combo_u, pair_u, xu1,
                                               nullptr, nullptr, nullptr, nullptr, nullptr, nullptr, NU);
        // pass 5: xr2 + fused rec_out epilogue (f32 concat init)
        gather_rows<1><<<GB_R, B, 0, stream>>>(xu1, combo_r, pair_r, xr2,
                                               rec_out, xr0, xr1, rcp_emb, rfeat, nullptr, NR);
        // pass 6: fused usr_out epilogue (bf16 init from emb_h), no x write
        gather_rows<2><<<GB_U, B, 0, stream>>>(xr2, combo_u, pair_u, nullptr,
                                               usr_out, xu0, xu1, nullptr, nullptr, emb_h, NU);
    } else {
        long long tot = (long long)(NU + NR) * D;
        init_out_kernel<<<(int)((tot + B - 1) / B), B, 0, stream>>>(usr_emb, rcp_emb, rfeat, out);
        gather_rows_acc<<<GB_R, B, 0, stream>>>(emb_h, combo_r, pair_r, xr0, rec_out, NR);
        gather_rows_acc<<<GB_U, B, 0, stream>>>(xr0, combo_u, pair_u, xu0, usr_out, NU);
        gather_rows_acc<<<GB_R, B, 0, stream>>>(xu0, combo_r, pair_r, xr0, rec_out, NR);
        gather_rows_acc<<<GB_U, B, 0, stream>>>(xr0, combo_u, pair_u, xu0, usr_out, NU);
        gather_rows_acc<<<GB_R, B, 0, stream>>>(xu0, combo_r, pair_r, xr0, rec_out, NR);
        gather_rows_acc<<<GB_U, B, 0, stream>>>(xr0, combo_u, pair_u, nullptr, usr_out, NU);
    }
}